// Round 1
// baseline (258.901 us; speedup 1.0000x reference)
//
#include <hip/hip_runtime.h>
#include <hip/hip_bf16.h>

// (B, LIN, E, D, N) = (32, 2048, 512, 512, 2)
#define L_SZ 2048
#define E_SZ 512
#define D_SZ 512
#define ND   1024
// ws layout: dec_proj (32*512 f32) | Bt (512*512 bf16, [n][k]) | scores (32*2048 f32)
#define WS_DEC_OFF 0
#define WS_BT_OFF  (32*512*4)
#define WS_SC_OFF  (32*512*4 + 512*512*2)

typedef unsigned short ushort_t;
typedef unsigned int   uint_t;
typedef __attribute__((ext_vector_type(8))) short short8;   // 8 bf16 (MFMA A/B frag)
typedef __attribute__((ext_vector_type(4))) float floatx4;  // MFMA C/D frag

__device__ __forceinline__ ushort_t f2bf(float f) {
  uint_t u = __builtin_bit_cast(uint_t, f);
  u += 0x7fffu + ((u >> 16) & 1u);
  return (ushort_t)(u >> 16);
}

__device__ __forceinline__ float fast_tanh(float x) {
  float e = __expf(2.0f * x);
  return 1.0f - 2.0f * __builtin_amdgcn_rcpf(e + 1.0f);
}

// ---------------------------------------------------------------------------
// Prep, 512 blocks:
//  blocks 0..255  : dec_proj[b][d] (b=blk>>3, d-tile=blk&7), k split 4-way + LDS reduce
//  blocks 256..511: Bt[n][k] = bf16(W1[1024+k][n]) via 32x32 LDS transpose tiles
// ---------------------------------------------------------------------------
__global__ __launch_bounds__(256) void prep_k(const float* __restrict__ dh,
                                              const float* __restrict__ W1,
                                              const float* __restrict__ b1,
                                              float* __restrict__ dec,
                                              ushort_t* __restrict__ Bt) {
  int blk = blockIdx.x, t = threadIdx.x;
  if (blk < 256) {
    int b = blk >> 3, d = (blk & 7) * 64 + (t & 63);
    int q = t >> 6;
    __shared__ float red[4][64];
    const float* dfb = dh + b * ND;
    float s = 0.f;
    #pragma unroll 8
    for (int k = q * 256; k < q * 256 + 256; k++)
      s = fmaf(dfb[k], W1[k * D_SZ + d], s);
    red[q][t & 63] = s;
    __syncthreads();
    if (q == 0)
      dec[b * D_SZ + d] = red[0][t] + red[1][t] + red[2][t] + red[3][t] + b1[d];
  } else {
    int tid = blk - 256;
    int tk = (tid >> 4) * 32, tn = (tid & 15) * 32;
    __shared__ float tile[32][33];
    int cc = t & 31, r8 = t >> 5;
    #pragma unroll
    for (int p = 0; p < 4; p++) {
      int r = r8 + p * 8;
      tile[r][cc] = W1[(ND + tk + r) * D_SZ + tn + cc];
    }
    __syncthreads();
    #pragma unroll
    for (int p = 0; p < 4; p++) {
      int nn = r8 + p * 8;
      Bt[(tn + nn) * E_SZ + tk + cc] = f2bf(tile[cc][nn]);
    }
  }
}

// ---------------------------------------------------------------------------
// Main: WG = 512 threads (8 waves) = 64 rows (one b,l-tile) x ALL 512 cols.
// K = 512 in 8 windows of BK=64. A (enc) read from HBM exactly once.
// Wave w owns cols [w*64, w*64+64): 4 mt x 4 nt tiles of 16x16x32, acc[4][4]=64 regs.
//
// B (Bt, 512 KB bf16) is L2-resident for the whole kernel -> fragments are read
// DIRECTLY L2->VGPR (8 x short8 per wave per window, 64B-line coalesced via the
// quad layout). No LDS staging for B at all: removes ~2/3 of the LDS traffic and
// the vmcnt(0)-draining second barrier per window.
// A staged via register round-trip into a DOUBLE-BUFFERED 64x64 bf16 LDS tile
// (XOR-swizzled rows -> conflict-free ds_read_b128), one barrier per window.
// LDS = 16.25 KB; target VGPR <= 128 (launch_bounds 512,4) -> 2 WGs/CU.
// ---------------------------------------------------------------------------
__global__ __launch_bounds__(512, 4) void main_k(const float* __restrict__ enc,
                                                 const ushort_t* __restrict__ Bt,
                                                 const float* __restrict__ dec,
                                                 const float* __restrict__ w2,
                                                 float* __restrict__ scores) {
  const int b  = blockIdx.y;
  const int l0 = blockIdx.x * 64;
  const int t  = threadIdx.x;            // 0..511
  const int wave = t >> 6, lane = t & 63;
  const int col = lane & 15, quad = lane >> 4;

  __shared__ __align__(16) ushort_t As[2][64 * 64];  // 2 x 8 KB, double-buffered
  __shared__ float s_sc[64];

  if (t < 64) s_sc[t] = 0.f;

  floatx4 acc[4][4];
  #pragma unroll
  for (int mt = 0; mt < 4; mt++)
    #pragma unroll
    for (int nt = 0; nt < 4; nt++)
      acc[mt][nt] = (floatx4){0.f, 0.f, 0.f, 0.f};

  const float* arow = enc + (size_t)(b * L_SZ + l0) * E_SZ;

  // A: thread t owns chunk t: row am, chunk ac (8 floats -> 8 bf16 = 16B)
  const int am = t >> 3, ac = t & 7;
  const float* aptr = arow + am * E_SZ + ac * 8;
  const int awoff = am * 64 + ((ac ^ (am & 7)) << 3);

  // B fragment base pointers: lane (col, quad) reads Bt[n][k-chunk], n = wave*64+nt*16+col.
  // quads 0..3 cover one contiguous 64B k-chunk per row -> full-line L2 requests.
  const ushort_t* bp0 = Bt + (wave * 64 + col) * E_SZ + quad * 8;
  const ushort_t* bp1 = bp0 + 16 * E_SZ;
  const ushort_t* bp2 = bp0 + 32 * E_SZ;
  const ushort_t* bp3 = bp0 + 48 * E_SZ;

  float4 pa = *(const float4*)aptr;
  float4 pb = *(const float4*)(aptr + 4);

  // prologue: stage A window 0 into As[0], prefetch A window 1
  {
    union { short8 v; __hip_bfloat162 h[4]; } pk;
    pk.h[0] = __float22bfloat162_rn(make_float2(pa.x, pa.y));
    pk.h[1] = __float22bfloat162_rn(make_float2(pa.z, pa.w));
    pk.h[2] = __float22bfloat162_rn(make_float2(pb.x, pb.y));
    pk.h[3] = __float22bfloat162_rn(make_float2(pb.z, pb.w));
    *(short8*)&As[0][awoff] = pk.v;
  }
  {
    const float* ap = aptr + 64;
    pa = *(const float4*)ap;
    pb = *(const float4*)(ap + 4);
  }
  __syncthreads();

  #pragma unroll 1
  for (int kw = 0; kw < 8; kw++) {
    // ---- B fragments for THIS window: 8 x 16B straight from L2 (issued first,
    //      consumed after A staging + ds_reads -> latency mostly covered) ----
    short8 bfr[8];
    bfr[0] = *(const short8*)(bp0);  bfr[4] = *(const short8*)(bp0 + 32);
    bfr[1] = *(const short8*)(bp1);  bfr[5] = *(const short8*)(bp1 + 32);
    bfr[2] = *(const short8*)(bp2);  bfr[6] = *(const short8*)(bp2 + 32);
    bfr[3] = *(const short8*)(bp3);  bfr[7] = *(const short8*)(bp3 + 32);
    bp0 += 64; bp1 += 64; bp2 += 64; bp3 += 64;

    // ---- stage A(kw+1) into the other buffer; prefetch A(kw+2) regs ----
    if (kw < 7) {
      union { short8 v; __hip_bfloat162 h[4]; } pk;
      pk.h[0] = __float22bfloat162_rn(make_float2(pa.x, pa.y));
      pk.h[1] = __float22bfloat162_rn(make_float2(pa.z, pa.w));
      pk.h[2] = __float22bfloat162_rn(make_float2(pb.x, pb.y));
      pk.h[3] = __float22bfloat162_rn(make_float2(pb.z, pb.w));
      *(short8*)&As[(kw + 1) & 1][awoff] = pk.v;
      if (kw < 6) {
        const float* ap = aptr + (kw + 2) * 64;
        pa = *(const float4*)ap;
        pb = *(const float4*)(ap + 4);
      }
    }

    // ---- MFMA: 2 k-steps of 32 on As[kw&1] ----
    const ushort_t* Acur = &As[kw & 1][0];
    #pragma unroll
    for (int ks = 0; ks < 2; ks++) {
      short8 af[4];
      #pragma unroll
      for (int mt = 0; mt < 4; mt++) {
        int m = mt * 16 + col;
        af[mt] = *(const short8*)&Acur[m * 64 + ((((ks << 2) + quad) ^ (m & 7)) << 3)];
      }
      #pragma unroll
      for (int mt = 0; mt < 4; mt++)
        #pragma unroll
        for (int nt = 0; nt < 4; nt++)
          acc[mt][nt] = __builtin_amdgcn_mfma_f32_16x16x32_bf16(af[mt], bfr[ks * 4 + nt], acc[mt][nt], 0, 0, 0);
    }

    __syncthreads();  // A(kw+1) writes visible; readers of As[kw&1] done
  }

  // ---- epilogue: tanh(acc + dec) . w2, reduced over n ----
  // C/D: D[row=quad*4+r][col] => m = mt*16+quad*4+r, n = wave*64+nt*16+col
  const float* decb = dec + b * D_SZ;
  float sums[4][4];
  #pragma unroll
  for (int mt = 0; mt < 4; mt++)
    #pragma unroll
    for (int r = 0; r < 4; r++) sums[mt][r] = 0.f;

  #pragma unroll
  for (int nt = 0; nt < 4; nt++) {
    int n = wave * 64 + nt * 16 + col;
    float dv = decb[n];
    float wv = w2[n];
    #pragma unroll
    for (int mt = 0; mt < 4; mt++)
      #pragma unroll
      for (int r = 0; r < 4; r++)
        sums[mt][r] += fast_tanh(acc[mt][nt][r] + dv) * wv;
  }
  #pragma unroll
  for (int mt = 0; mt < 4; mt++) {
    #pragma unroll
    for (int r = 0; r < 4; r++) {
      float v = sums[mt][r];
      v += __shfl_xor(v, 1, 16);
      v += __shfl_xor(v, 2, 16);
      v += __shfl_xor(v, 4, 16);
      v += __shfl_xor(v, 8, 16);
      if (col == 0) atomicAdd(&s_sc[mt * 16 + quad * 4 + r], v);  // 8 waves/row
    }
  }
  __syncthreads();
  if (t < 64) scores[b * L_SZ + l0 + t] = s_sc[t];
}

// ---------------------------------------------------------------------------
// Softmax: one WG (1024 threads) per batch row of 2048.
// ---------------------------------------------------------------------------
__global__ __launch_bounds__(1024) void softmax_k(const float* __restrict__ sc,
                                                  float* __restrict__ out) {
  int b = blockIdx.x, t = threadIdx.x;
  int wave = t >> 6, lane = t & 63;
  __shared__ float redm[16], reds[16];
  const float* row = sc + b * L_SZ;
  float v0 = row[t], v1 = row[t + 1024];
  float mx = fmaxf(v0, v1);
  #pragma unroll
  for (int off = 32; off >= 1; off >>= 1) mx = fmaxf(mx, __shfl_xor(mx, off, 64));
  if (lane == 0) redm[wave] = mx;
  __syncthreads();
  float m = redm[0];
  #pragma unroll
  for (int i = 1; i < 16; i++) m = fmaxf(m, redm[i]);
  v0 = __expf(v0 - m);
  v1 = __expf(v1 - m);
  float s = v0 + v1;
  #pragma unroll
  for (int off = 32; off >= 1; off >>= 1) s += __shfl_xor(s, off, 64);
  if (lane == 0) reds[wave] = s;
  __syncthreads();
  float sum = reds[0];
  #pragma unroll
  for (int i = 1; i < 16; i++) sum += reds[i];
  float inv = 1.0f / sum;
  out[b * L_SZ + t]        = v0 * inv;
  out[b * L_SZ + t + 1024] = v1 * inv;
}

extern "C" void kernel_launch(void* const* d_in, const int* in_sizes, int n_in,
                              void* d_out, int out_size, void* d_ws, size_t ws_size,
                              hipStream_t stream) {
  const float* d_hidden = (const float*)d_in[0];   // (32, 2, 512)
  const float* enc      = (const float*)d_in[1];   // (32, 2048, 512)
  const float* W1       = (const float*)d_in[2];   // (1536, 512)
  const float* b1       = (const float*)d_in[3];   // (512,)
  const float* w2       = (const float*)d_in[4];   // (512,)
  float* out = (float*)d_out;                      // (32, 2048)

  char* ws = (char*)d_ws;
  float*    dec = (float*)(ws + WS_DEC_OFF);
  ushort_t* Bt  = (ushort_t*)(ws + WS_BT_OFF);
  float*    sc  = (float*)(ws + WS_SC_OFF);

  prep_k<<<512, 256, 0, stream>>>(d_hidden, W1, b1, dec, Bt);
  main_k<<<dim3(32, 32), 512, 0, stream>>>(enc, Bt, dec, w2, sc);
  softmax_k<<<32, 1024, 0, stream>>>(sc, out);
}